// Round 1
// baseline (471.048 us; speedup 1.0000x reference)
//
#include <hip/hip_runtime.h>

typedef unsigned short u16;
typedef short bf16x8 __attribute__((ext_vector_type(8)));   // 8 bf16 = 4 VGPRs
typedef u16 u16x8 __attribute__((ext_vector_type(8)));
typedef float f32x4 __attribute__((ext_vector_type(4)));

__device__ __forceinline__ u16 f2bf(float f) {
  unsigned u = __builtin_bit_cast(unsigned, f);
  unsigned r = (u + 0x7fffu + ((u >> 16) & 1u)) >> 16;   // RNE, values are tame (no NaN/Inf)
  return (u16)r;
}
__device__ __forceinline__ float bf2f(u16 h) {
  unsigned u = ((unsigned)h) << 16;
  return __builtin_bit_cast(float, u);
}

#define GLDS16(g, l) __builtin_amdgcn_global_load_lds(                        \
    (const __attribute__((address_space(1))) unsigned int*)(g),               \
    (__attribute__((address_space(3))) unsigned int*)(l), 16, 0, 0)

// ---------------- prep 1: qv[t][q] = cos(x[t*512+q]) * cos(theta[q]) ----------------
__global__ void k_qv(const float* __restrict__ x, const float* __restrict__ theta,
                     float* __restrict__ qv, int total) {
  int i = blockIdx.x * blockDim.x + threadIdx.x;
  if (i >= total) return;
  int q = i & 7;
  int t = i >> 3;
  qv[i] = cosf(x[(t << 9) + q]) * cosf(theta[q]);
}

// ---------------- prep 2: W2 -> split bf16 hi/lo, tile-linear + slot-XOR swizzled ----
// LDS-matched layout: bf16 index i = [ntile(2)][kp(32)][col(256)][sp(8)][jj(8)]
// content at physical slot sp is data slot sp^(col&7):  f = kp*64 + (sp^(col&7))*8 + jj
__global__ void k_w2prep(const float* __restrict__ W2, u16* __restrict__ hi,
                         u16* __restrict__ lo) {
  int i = blockIdx.x * blockDim.x + threadIdx.x;   // 0 .. 2*32*256*64-1
  int jj = i & 7;
  int sp = (i >> 3) & 7;
  int col = (i >> 6) & 255;
  int kp  = (i >> 14) & 31;
  int ntile = i >> 19;
  int e = (ntile << 8) + col;
  int f = (kp << 6) + (((sp ^ (col & 7)) << 3) | jj);
  float v = W2[(e << 11) + f];
  u16 h = f2bf(v);
  hi[i] = h;
  lo[i] = f2bf(v - bf2f(h));
}

// ---------------- main fused kernel ----------------
// out[t][e] = sum_f relu(b1[f] + sum_q qv[t][q]*W1[f][q]) * W2[e][f] + b2[e]
// GEMM M=32768, N=512, K=2048.  BM=128 BN=256 BK=64, 512 thr (8 waves 2Mx4N).
// 3-term split-bf16 MFMA (a_hi*b_hi + a_lo*b_hi + a_hi*b_lo) ~ fp32 accuracy.
#define BM 128
#define BN 256
#define NKP 32     // 2048/64
#define EDIM 512

__global__ __launch_bounds__(512, 2) void k_ffq(
    const float* __restrict__ qv,
    const u16* __restrict__ bhi, const u16* __restrict__ blo,
    const float* __restrict__ W1, const float* __restrict__ b1,
    const float* __restrict__ b2, float* __restrict__ out)
{
  extern __shared__ char smem[];
  char* sBhi = smem;             // 32768 B: [col(256)][slot(8)][16B]
  char* sBlo = smem + 32768;     // 32768 B
  char* sAhi = smem + 65536;     // 16384 B: [row(128)][slot(8)][16B]
  char* sAlo = smem + 81920;     // 16384 B

  const int tid  = threadIdx.x;
  const int lane = tid & 63;
  const int wid  = tid >> 6;

  const int nt = blockIdx.x & 1;
  const int mt = blockIdx.x >> 1;

  // ---- H-compute assignment: this lane owns token row tloc for the whole kernel
  const int tloc = ((wid & 1) << 6) | lane;            // 0..127
  const float4* qp = (const float4*)(qv + ((mt * BM + tloc) << 3));
  const float4 q0 = qp[0], q1 = qp[1];                 // qv[t][0..7] resident in VGPRs
  const int slotbase = (wid >> 1) << 1;                // waves pair-cover 64 f per panel

  // ---- GEMM wave tile: 64x64 per wave
  const int wr = wid >> 2;
  const int wc = wid & 3;

  f32x4 acc[4][4];
#pragma unroll
  for (int i = 0; i < 4; ++i)
#pragma unroll
    for (int j = 0; j < 4; ++j) acc[i][j] = (f32x4){0.f, 0.f, 0.f, 0.f};

  const u16* gBhi = bhi + ((unsigned)(nt * NKP) << 14);
  const u16* gBlo = blo + ((unsigned)(nt * NKP) << 14);

  for (int kp = 0; kp < NKP; ++kp) {
    __syncthreads();   // previous iteration's readers are done with LDS

    // ---- stage B panel (64 KB) via global_load_lds, width 16, linear dest
    {
      const char* ghi = (const char*)(gBhi + (kp << 14));
      const char* glo = (const char*)(gBlo + (kp << 14));
#pragma unroll
      for (int i = 0; i < 4; ++i) {
        const int off = (((i << 3) | wid) << 10);      // per-wave 1 KB chunks
        GLDS16(ghi + off + lane * 16, sBhi + off);
        GLDS16(glo + off + lane * 16, sBlo + off);
      }
    }

    // ---- compute A (H) tile: 16 h per lane = 2 groups of 8 consecutive f
    {
#pragma unroll
      for (int g = 0; g < 2; ++g) {
        const int slot = slotbase | g;                 // data slot 0..7
        const int fg = (kp << 6) | (slot << 3);        // first f of this group
        const float4* b1p = (const float4*)(b1 + fg);
        const float4 bva = b1p[0], bvb = b1p[1];
        const float bv[8] = {bva.x, bva.y, bva.z, bva.w, bvb.x, bvb.y, bvb.z, bvb.w};
        float h[8];
#pragma unroll
        for (int r = 0; r < 8; ++r) {
          const float4* w1p = (const float4*)(W1 + ((fg + r) << 3));  // wave-uniform
          const float4 wa = w1p[0], wb = w1p[1];
          float s = bv[r];
          s = fmaf(q0.x, wa.x, s); s = fmaf(q0.y, wa.y, s);
          s = fmaf(q0.z, wa.z, s); s = fmaf(q0.w, wa.w, s);
          s = fmaf(q1.x, wb.x, s); s = fmaf(q1.y, wb.y, s);
          s = fmaf(q1.z, wb.z, s); s = fmaf(q1.w, wb.w, s);
          h[r] = fmaxf(s, 0.f);
        }
        u16x8 hi8, lo8;
#pragma unroll
        for (int r = 0; r < 8; ++r) {
          u16 hb = f2bf(h[r]);
          hi8[r] = hb;
          lo8[r] = f2bf(h[r] - bf2f(hb));
        }
        const int bo = (tloc << 7) | ((slot ^ (tloc & 7)) << 4);   // swizzled
        *(u16x8*)(sAhi + bo) = hi8;
        *(u16x8*)(sAlo + bo) = lo8;
      }
    }

    __syncthreads();   // drains vmcnt (global_load_lds) + lgkm, all writes visible

    // ---- MFMA: 2 k-fragments x 16 (mi,ni) x 3 split terms = 96 MFMAs/wave
#pragma unroll
    for (int kf = 0; kf < 2; ++kf) {
      const int sr = (kf << 2) | (lane >> 4);          // data slot to read
      bf16x8 ah[4], al[4];
#pragma unroll
      for (int mi = 0; mi < 4; ++mi) {
        const int row = (wr << 6) | (mi << 4) | (lane & 15);
        const int bo = (row << 7) | ((sr ^ (row & 7)) << 4);
        ah[mi] = *(const bf16x8*)(sAhi + bo);
        al[mi] = *(const bf16x8*)(sAlo + bo);
      }
#pragma unroll
      for (int ni = 0; ni < 4; ++ni) {
        const int col = (wc << 6) | (ni << 4) | (lane & 15);
        const int bo = (col << 7) | ((sr ^ (col & 7)) << 4);
        const bf16x8 bh = *(const bf16x8*)(sBhi + bo);
        const bf16x8 bl = *(const bf16x8*)(sBlo + bo);
#pragma unroll
        for (int mi = 0; mi < 4; ++mi) {
          acc[mi][ni] = __builtin_amdgcn_mfma_f32_16x16x32_bf16(ah[mi], bh, acc[mi][ni], 0, 0, 0);
          acc[mi][ni] = __builtin_amdgcn_mfma_f32_16x16x32_bf16(al[mi], bh, acc[mi][ni], 0, 0, 0);
          acc[mi][ni] = __builtin_amdgcn_mfma_f32_16x16x32_bf16(ah[mi], bl, acc[mi][ni], 0, 0, 0);
        }
      }
    }
  }

  // ---- epilogue: D[row=(lane>>4)*4+r][col=lane&15] per fragment (m89-verified layout)
#pragma unroll
  for (int ni = 0; ni < 4; ++ni) {
    const int col = (nt << 8) | (wc << 6) | (ni << 4) | (lane & 15);
    const float b2v = b2[col];
#pragma unroll
    for (int mi = 0; mi < 4; ++mi) {
      const int row0 = mt * BM + ((wr << 6) | (mi << 4) | ((lane >> 4) << 2));
      float* op = out + row0 * EDIM + col;
#pragma unroll
      for (int r = 0; r < 4; ++r)
        op[r * EDIM] = acc[mi][ni][r] + b2v;
    }
  }
}

extern "C" void kernel_launch(void* const* d_in, const int* in_sizes, int n_in,
                              void* d_out, int out_size, void* d_ws, size_t ws_size,
                              hipStream_t stream) {
  const float* x     = (const float*)d_in[0];
  const float* theta = (const float*)d_in[1];
  const float* W1    = (const float*)d_in[2];
  const float* b1    = (const float*)d_in[3];
  const float* W2    = (const float*)d_in[4];
  const float* b2    = (const float*)d_in[5];
  float* out = (float*)d_out;

  const int M = in_sizes[0] / 512;           // 32768 tokens

  float* qv = (float*)d_ws;                              // 1 MiB
  u16* bhi  = (u16*)((char*)d_ws + (1u << 20));          // 2 MiB
  u16* blo  = (u16*)((char*)d_ws + (3u << 20));          // 2 MiB

  const int totq = M * 8;
  k_qv<<<(totq + 255) / 256, 256, 0, stream>>>(x, theta, qv, totq);
  k_w2prep<<<1048576 / 256, 256, 0, stream>>>(W2, bhi, blo);
  k_ffq<<<dim3((M / BM) * 2), 512, 98304, stream>>>(qv, bhi, blo, W1, b1, b2, out);
}